// Round 6
// baseline (321.882 us; speedup 1.0000x reference)
//
#include <hip/hip_runtime.h>
#include <hip/hip_bf16.h>
#include <math.h>

namespace {
constexpr int kD = 256;      // embed dim
constexpr int kDOUT = 256;   // out dim
constexpr int kNQ = 65536;   // num query nodes
constexpr int kE = 262144;   // edges
constexpr float kAlpha = 0.2f;
constexpr float kEps = 1e-12f;
}

typedef short bf16x8 __attribute__((ext_vector_type(8)));
typedef float f32x4 __attribute__((ext_vector_type(4)));

// c[j] = sum_k a[k][j] * a2[k]   (a is (DOUT, 2D) row-major; j in [0, 512))
__global__ void compute_c_kernel(const float* __restrict__ a,
                                 const float* __restrict__ a2,
                                 float* __restrict__ c) {
  const int j = blockIdx.x * blockDim.x + threadIdx.x;  // 0..511
  float s = 0.f;
#pragma unroll 8
  for (int k = 0; k < kDOUT; ++k) s = fmaf(a[k * (2 * kD) + j], a2[k], s);
  c[j] = s;
}

// zero count[NQ] + rowsum[NQ] (adjacent) with a properly-sized grid
__global__ void zero_kernel(int4* __restrict__ p) {
  p[blockIdx.x * 256 + threadIdx.x] = int4{0, 0, 0, 0};
}

// trans (256x256 f32) -> bf16
__global__ void cvt_trans_kernel(const float* __restrict__ t, ushort* __restrict__ tb) {
  const int i = blockIdx.x * 256 + threadIdx.x;  // 4 elems each
  const float4 v = reinterpret_cast<const float4*>(t)[i];
  union { ushort4 u; __hip_bfloat16 h[4]; } p;
  p.h[0] = __float2bfloat16(v.x);
  p.h[1] = __float2bfloat16(v.y);
  p.h[2] = __float2bfloat16(v.z);
  p.h[3] = __float2bfloat16(v.w);
  reinterpret_cast<ushort4*>(tb)[i] = p.u;
}

// histogram of query_list into count[]
__global__ __launch_bounds__(256) void hist_kernel(const int* __restrict__ query_list,
                                                   int* __restrict__ count) {
  const int i = blockIdx.x * 256 + threadIdx.x;
  const int4 q = reinterpret_cast<const int4*>(query_list)[i];
  atomicAdd(&count[q.x], 1);
  atomicAdd(&count[q.y], 1);
  atomicAdd(&count[q.z], 1);
  atomicAdd(&count[q.w], 1);
}

// Single-block exclusive scan of count[NQ] -> offsets, cursor copy.
__global__ __launch_bounds__(1024) void scan_kernel(const int* __restrict__ count,
                                                    int* __restrict__ offsets,
                                                    int* __restrict__ cursor) {
  __shared__ int partial[1024];
  const int t = threadIdx.x;
  int4 loc[16];
#pragma unroll
  for (int i = 0; i < 16; ++i) loc[i] = reinterpret_cast<const int4*>(count)[t * 16 + i];
  int s = 0;
#pragma unroll
  for (int i = 0; i < 16; ++i) s += loc[i].x + loc[i].y + loc[i].z + loc[i].w;
  partial[t] = s;
  __syncthreads();
  for (int off = 1; off < 1024; off <<= 1) {
    int v = (t >= off) ? partial[t - off] : 0;
    __syncthreads();
    partial[t] += v;
    __syncthreads();
  }
  int run = partial[t] - s;
#pragma unroll
  for (int i = 0; i < 16; ++i) {
    const int4 v = loc[i];
    int4 o;
    o.x = run; run += v.x;
    o.y = run; run += v.y;
    o.z = run; run += v.z;
    o.w = run; run += v.w;
    reinterpret_cast<int4*>(offsets)[t * 16 + i] = o;
    reinterpret_cast<int4*>(cursor)[t * 16 + i] = o;
  }
  if (t == 1023) offsets[kNQ] = run;  // == E
}

// Pass 1 (sequential over edges): one wave per edge.
// Read key/query rows (seq), compute ev = exp(-leaky(key.ck + query.cq)),
// claim CSR slot, accumulate rowsum[q], scatter-write bf16(ev*key_row)
// into csr_buf[pos]. Randomness lives only on the 512B posted writes.
__global__ __launch_bounds__(256) void edge_scatter_kernel(
    const float* __restrict__ key_embed,
    const float* __restrict__ query_embed,
    const int* __restrict__ query_list,
    const float* __restrict__ c,
    int* __restrict__ cursor,
    float* __restrict__ rowsum,
    ushort* __restrict__ csr_buf) {
  const int edge = (blockIdx.x << 2) + (threadIdx.x >> 6);
  const int lane = threadIdx.x & 63;

  const float4 k4 = reinterpret_cast<const float4*>(key_embed)[(size_t)edge * (kD / 4) + lane];
  const float4 q4 = reinterpret_cast<const float4*>(query_embed)[(size_t)edge * (kD / 4) + lane];
  const float4 ck = reinterpret_cast<const float4*>(c)[lane];
  const float4 cq = reinterpret_cast<const float4*>(c)[64 + lane];

  float s = k4.x * ck.x + k4.y * ck.y + k4.z * ck.z + k4.w * ck.w
          + q4.x * cq.x + q4.y * cq.y + q4.z * cq.z + q4.w * cq.w;
#pragma unroll
  for (int off = 32; off > 0; off >>= 1) s += __shfl_xor(s, off, 64);

  const float p = (s > 0.f) ? s : kAlpha * s;   // leaky_relu
  const float ev = __expf(-p);

  int pos = 0;
  if (lane == 0) {
    const int q = query_list[edge];
    pos = atomicAdd(&cursor[q], 1);
    unsafeAtomicAdd(&rowsum[q], ev);
  }
  pos = __shfl(pos, 0, 64);

  union { ushort4 u; __hip_bfloat16 h[4]; } pk;
  pk.h[0] = __float2bfloat16(ev * k4.x);
  pk.h[1] = __float2bfloat16(ev * k4.y);
  pk.h[2] = __float2bfloat16(ev * k4.z);
  pk.h[3] = __float2bfloat16(ev * k4.w);
  *reinterpret_cast<ushort4*>(csr_buf + (size_t)pos * kD + lane * 4) = pk.u;
}

// Pass 2 (fully sequential): one wave per query. Sum the contiguous bf16
// CSR segment in f32, normalize by rowsum, write bf16 accb row.
__global__ __launch_bounds__(256) void segsum_kernel(
    const ushort* __restrict__ csr_buf,
    const int* __restrict__ offsets,
    const float* __restrict__ rowsum,
    ushort* __restrict__ accb) {
  const int q = (blockIdx.x << 2) + (threadIdx.x >> 6);
  const int lane = threadIdx.x & 63;
  const int s0 = offsets[q], s1 = offsets[q + 1];

  float4 a = {0.f, 0.f, 0.f, 0.f};
  for (int i = s0; i < s1; ++i) {
    union { ushort4 u; __hip_bfloat16 h[4]; } r;
    r.u = *reinterpret_cast<const ushort4*>(csr_buf + (size_t)i * kD + lane * 4);
    a.x += __bfloat162float(r.h[0]);
    a.y += __bfloat162float(r.h[1]);
    a.z += __bfloat162float(r.h[2]);
    a.w += __bfloat162float(r.h[3]);
  }

  const float rs = rowsum[q];
  const float inv = 1.0f / ((rs == 0.f) ? kEps : rs);
  union { ushort4 u; __hip_bfloat16 h[4]; } p;
  p.h[0] = __float2bfloat16(a.x * inv);
  p.h[1] = __float2bfloat16(a.y * inv);
  p.h[2] = __float2bfloat16(a.z * inv);
  p.h[3] = __float2bfloat16(a.w * inv);
  *reinterpret_cast<ushort4*>(accb + (size_t)q * kD + lane * 4) = p.u;
}

// out = elu(A @ B^T).  A: (NQ,256) bf16 row-major (pre-normalized), B = trans bf16.
// One wave per 16-row strip, full N=256 in registers (16 n-tiles of 16x16x32 MFMA).
__global__ __launch_bounds__(256) void out_gemm_mfma_kernel(
    const ushort* __restrict__ A,
    const ushort* __restrict__ B,
    float* __restrict__ out) {
  const int wid = threadIdx.x >> 6;
  const int lane = threadIdx.x & 63;
  const int row0 = (blockIdx.x * 4 + wid) * 16;
  const int m = lane & 15;
  const int kb = (lane >> 4) * 8;

  f32x4 acc[16] = {};

  for (int kt = 0; kt < kD; kt += 32) {
    const bf16x8 af = *reinterpret_cast<const bf16x8*>(&A[(size_t)(row0 + m) * kD + kt + kb]);
#pragma unroll
    for (int nt = 0; nt < 16; ++nt) {
      const bf16x8 bf = *reinterpret_cast<const bf16x8*>(&B[(size_t)(nt * 16 + m) * kD + kt + kb]);
      acc[nt] = __builtin_amdgcn_mfma_f32_16x16x32_bf16(af, bf, acc[nt], 0, 0, 0);
    }
  }

#pragma unroll
  for (int nt = 0; nt < 16; ++nt) {
#pragma unroll
    for (int r = 0; r < 4; ++r) {
      const int row = row0 + (lane >> 4) * 4 + r;
      const int col = nt * 16 + (lane & 15);
      const float x = acc[nt][r];
      out[(size_t)row * kDOUT + col] = (x > 0.f) ? x : expm1f(x);
    }
  }
}

extern "C" void kernel_launch(void* const* d_in, const int* in_sizes, int n_in,
                              void* d_out, int out_size, void* d_ws, size_t ws_size,
                              hipStream_t stream) {
  // inputs: 0 key_list(int,E) [unused], 1 key_embed(f32,E*256), 2 query_list(int,E),
  //         3 query_embed(f32,E*256), 4 a(f32,256*512), 5 a_2(f32,256), 6 trans(f32,256*256)
  const float* key_embed = (const float*)d_in[1];
  const int* query_list = (const int*)d_in[2];
  const float* query_embed = (const float*)d_in[3];
  const float* a = (const float*)d_in[4];
  const float* a2 = (const float*)d_in[5];
  const float* trans = (const float*)d_in[6];
  float* out = (float*)d_out;

  // workspace layout (float units, all 16B-aligned):
  // c[512] | count[NQ] | rowsum[NQ] | cursor[NQ] | offsets[NQ+4]
  // | csr_buf[E*256 ushort] | accb[NQ*256 ushort] | transb[256*256 ushort]
  float* ws = (float*)d_ws;
  float* c = ws;
  int* count = (int*)(ws + 512);
  float* rowsum = (float*)(count + kNQ);
  int* cursor = (int*)(rowsum + kNQ);
  int* offsets = cursor + kNQ;
  float* base2 = (float*)(offsets + kNQ + 4);          // 512+4*NQ+4 floats: mult of 4
  ushort* csr_buf = (ushort*)base2;                     // E*256 bf16
  ushort* accb = (ushort*)(base2 + (size_t)kE * (kD / 2));
  ushort* transb = (ushort*)(base2 + (size_t)kE * (kD / 2) + (size_t)kNQ * (kD / 2));

  zero_kernel<<<2 * kNQ / 4 / 256, 256, 0, stream>>>((int4*)count);  // count + rowsum
  compute_c_kernel<<<2, 256, 0, stream>>>(a, a2, c);
  cvt_trans_kernel<<<kDOUT * kD / 4 / 256, 256, 0, stream>>>(trans, transb);
  hist_kernel<<<kE / 4 / 256, 256, 0, stream>>>(query_list, count);
  scan_kernel<<<1, 1024, 0, stream>>>(count, offsets, cursor);
  edge_scatter_kernel<<<kE / 4, 256, 0, stream>>>(key_embed, query_embed, query_list, c,
                                                  cursor, rowsum, csr_buf);
  segsum_kernel<<<kNQ / 4, 256, 0, stream>>>(csr_buf, offsets, rowsum, accb);
  out_gemm_mfma_kernel<<<kNQ / 64, 256, 0, stream>>>(accb, transb, out);
}